// Round 16
// baseline (374.304 us; speedup 1.0000x reference)
//
#include <hip/hip_runtime.h>
#include <cstdint>

constexpr int F        = 128;     // feature width (F_in == H == 128)
constexpr int U_CAP    = 8192;    // cap on |T ∪ in-nbrs(T)|; expected ~2.2k
constexpr int T_CAP    = 128;     // cap on |targets|; actual <= 66
constexpr int E2_CAP   = 131072;  // cap on edges into T; expected ~2.1k
constexpr int BKT      = 128;     // bucket slots per U-node (in-degree ~Poisson(32))
constexpr int BM_WORDS = 3200;    // membership bitmap: supports N <= 102400
constexpr int SBLK     = 256;     // scan block size
constexpr int EPT      = 64;      // edges per thread (16x int4, interleaved)
constexpr int EPBLK    = SBLK * EPT;  // 16384 edges per block
constexpr int LCAP     = 512;     // LDS staging cap (4 KB)

// hdr: [0]=nT [1]=nU [2]=nE2 [3]=unused [4]=edge_is_int64 [5]=nbr_is_int64

__global__ void k_zero(int* p, int n) {
    int i = blockIdx.x * blockDim.x + threadIdx.x;
    int stride = gridDim.x * blockDim.x;
    for (; i < n; i += stride) p[i] = 0;
}

// ---- 1. parallel dedup of targets + int64 detection (one block) ------------
__global__ void k_build(const int* eidx, int E, int N,
                        const int* curr, const int* dest, const int* nbr, int K,
                        int* hdr, int* t_map, int* u_map,
                        unsigned* t_bm, unsigned* u_bm,
                        int* t_node, int* ent2comp, int* ulist) {
    __shared__ int s_e64, s_n64;
    int tid = threadIdx.x;
    if (tid == 0) { s_e64 = 1; s_n64 = 1; }
    __syncthreads();
    if (tid < 64 && eidx[2 * tid + 1] != 0) s_e64 = 0;
    if (tid < K / 2 && nbr[2 * tid + 1] != 0) s_n64 = 0;
    __syncthreads();
    int n64 = s_n64;
    if (tid == 0) { hdr[4] = s_e64; hdr[5] = s_n64; }

    int node = -1;
    if (tid < K + 2) {
        if (tid == 0)      node = curr[0];
        else if (tid == 1) node = dest[0];
        else               node = n64 ? nbr[2 * (tid - 2)] : nbr[tid - 2];
        if ((unsigned)node < (unsigned)N) {
            if (atomicCAS(&t_map[node], 0, -1) == 0) {   // claim: one winner
                int slot = atomicAdd(&hdr[0], 1);
                t_node[slot] = node;
                int uid = atomicAdd(&hdr[1], 1);
                ulist[uid] = node;
                atomicExch(&u_map[node], uid + 1);
                if (node < BM_WORDS * 32) {
                    atomicOr(&t_bm[node >> 5], 1u << (node & 31));
                    atomicOr(&u_bm[node >> 5], 1u << (node & 31));
                }
                atomicExch(&t_map[node], slot + 1);      // publish final slot
            }
        }
    }
    __syncthreads();
    if (tid < K + 2) {
        int v = ((unsigned)node < (unsigned)N) ? atomicAdd(&t_map[node], 0) : 1;
        ent2comp[tid] = v - 1;
    }
}

static __device__ __forceinline__ int esrc(const int* eidx, int E, int e, int is64) {
    return is64 ? eidx[2 * (size_t)e] : eidx[e];
}
static __device__ __forceinline__ int edst(const int* eidx, int E, int e, int is64) {
    return is64 ? eidx[2 * ((size_t)E + e)] : eidx[(size_t)E + e];
}

// ---- 2. scan: edges into T (64 edges/thread, branchless L1 probes) ---------
__global__ void k_scan1(const int* __restrict__ eidx, int E, int N,
                        const int* __restrict__ t_map, int* u_map,
                        const unsigned* __restrict__ t_bm, unsigned* u_bm,
                        int* hdr, int2* edges2, int* ulist) {
    __shared__ int l_cnt, l_base;
    __shared__ int2 l_buf[LCAP];
    int tid = threadIdx.x;
    if (tid == 0) l_cnt = 0;
    __syncthreads();
    int is64 = hdr[4];
    int be = blockIdx.x * EPBLK;
    int dv[EPT];
    #pragma unroll
    for (int r = 0; r < EPT / 4; ++r) {
        int e0 = be + (r * SBLK + tid) * 4;
        if (!is64 && e0 + 3 < E) {
            int4 d4 = *reinterpret_cast<const int4*>(eidx + (size_t)E + e0);
            dv[r*4+0] = d4.x; dv[r*4+1] = d4.y; dv[r*4+2] = d4.z; dv[r*4+3] = d4.w;
        } else {
            for (int q = 0; q < 4; ++q)
                dv[r*4+q] = (e0 + q < E) ? edst(eidx, E, e0 + q, is64) : -1;
        }
    }
    unsigned long long m = 0;
    #pragma unroll
    for (int i = 0; i < EPT; ++i) {
        int d  = dv[i];
        int dc = ((unsigned)d < (unsigned)N) ? d : 0;
        unsigned w = t_bm[dc >> 5];
        if ((unsigned)d < (unsigned)N && ((w >> (d & 31)) & 1))
            m |= (1ull << i);
    }
    while (m) {
        int i = __ffsll(m) - 1; m &= m - 1;
        int d = dv[i];
        int tm = t_map[d];
        if (tm <= 0) continue;
        int r = i >> 2, q = i & 3;
        int e = be + (r * SBLK + tid) * 4 + q;
        int s = esrc(eidx, E, e, is64);
        if ((unsigned)s >= (unsigned)N) continue;
        int p = atomicAdd(&l_cnt, 1);
        if (p < LCAP) l_buf[p] = make_int2(s, tm - 1);
        else {
            int gp = atomicAdd(&hdr[2], 1);
            if (gp < E2_CAP) edges2[gp] = make_int2(s, tm - 1);
        }
        if (atomicCAS(&u_map[s], 0, -1) == 0) {
            int id = atomicAdd(&hdr[1], 1);
            if (id < U_CAP) ulist[id] = s;
            if (s < BM_WORDS * 32) atomicOr(&u_bm[s >> 5], 1u << (s & 31));
            __threadfence();
            atomicExch(&u_map[s], id + 1);
        }
    }
    __syncthreads();
    int c = min(l_cnt, LCAP);
    if (c > 0) {
        if (tid == 0) l_base = atomicAdd(&hdr[2], c);
        __syncthreads();
        for (int i = tid; i < c; i += SBLK) {
            int gp = l_base + i;
            if (gp < E2_CAP) edges2[gp] = l_buf[i];
        }
    }
}

// ---- 3. scan: edges into U -> per-dest buckets (64 edges/thread) -----------
__global__ void k_scanU(const int* __restrict__ eidx, int E, int N,
                        const int* __restrict__ u_map,
                        const unsigned* __restrict__ u_bm,
                        const int* __restrict__ hdr,
                        int* deg1, int* bucket) {
    int tid = threadIdx.x;
    int is64 = hdr[4];
    int be = blockIdx.x * EPBLK;
    int dv[EPT];
    #pragma unroll
    for (int r = 0; r < EPT / 4; ++r) {
        int e0 = be + (r * SBLK + tid) * 4;
        if (!is64 && e0 + 3 < E) {
            int4 d4 = *reinterpret_cast<const int4*>(eidx + (size_t)E + e0);
            dv[r*4+0] = d4.x; dv[r*4+1] = d4.y; dv[r*4+2] = d4.z; dv[r*4+3] = d4.w;
        } else {
            for (int q = 0; q < 4; ++q)
                dv[r*4+q] = (e0 + q < E) ? edst(eidx, E, e0 + q, is64) : -1;
        }
    }
    unsigned long long m = 0;
    #pragma unroll
    for (int i = 0; i < EPT; ++i) {
        int d  = dv[i];
        int dc = ((unsigned)d < (unsigned)N) ? d : 0;
        unsigned w = u_bm[dc >> 5];
        if ((unsigned)d < (unsigned)N && ((w >> (d & 31)) & 1))
            m |= (1ull << i);
    }
    while (m) {
        int i = __ffsll(m) - 1; m &= m - 1;
        int d = dv[i];
        int um = u_map[d];
        if (um <= 0 || um > U_CAP) continue;
        int r = i >> 2, q = i & 3;
        int e = be + (r * SBLK + tid) * 4 + q;
        int s = esrc(eidx, E, e, is64);
        if ((unsigned)s >= (unsigned)N) continue;
        int slot = um - 1;
        int pos = atomicAdd(&deg1[slot], 1);   // scalar atomic, 2.2k addresses
        if (pos < BKT) bucket[(size_t)slot * BKT + pos] = s;
    }
}

// ---- 4. fused layer-1: bucket mean + GEMV -> h (per U-node) ----------------
__global__ void k_l1(const int* __restrict__ deg1, const int* __restrict__ bucket,
                     const int* __restrict__ hdr, const int* __restrict__ ulist, int N,
                     const float* __restrict__ x,
                     const float* __restrict__ W1l, const float* __restrict__ W1r,
                     const float* __restrict__ b1, float* __restrict__ h) {
    int nU = min(hdr[1], U_CAP);
    __shared__ int s_src[BKT];
    __shared__ float mean[F];
    __shared__ float xr[F];
    int j = threadIdx.x;   // 128 threads
    for (int b = blockIdx.x; b < nU; b += gridDim.x) {
        int dg = deg1[b];
        int stored = min(dg, BKT);
        if (j < stored) s_src[j] = bucket[(size_t)b * BKT + j];
        int node = ulist[b];
        xr[j] = ((unsigned)node < (unsigned)N) ? x[(size_t)node * F + j] : 0.0f;
        __syncthreads();
        float acc = 0.0f;
        #pragma unroll 4
        for (int i = 0; i < stored; ++i) {
            int s = s_src[i];
            if ((unsigned)s < (unsigned)N) acc += x[(size_t)s * F + j];
        }
        float c = (dg < 1) ? 1.0f : (float)dg;
        mean[j] = acc / c;
        __syncthreads();
        float o = b1[j];
        #pragma unroll 4
        for (int k = 0; k < F; ++k) {
            o += mean[k] * W1l[k * F + j];
            o += xr[k]   * W1r[k * F + j];
        }
        h[(size_t)b * F + j] = (o > 0.0f) ? o : 0.0f;
        __syncthreads();   // protect LDS before next node
    }
}

// ---- 5. fused layer-2: filter edges2 + mean + GEMV -> embT (per target) ----
__global__ void k_l2(const int* __restrict__ hdr, const int* __restrict__ t_node,
                     const int* __restrict__ u_map, int N,
                     const int2* __restrict__ edges2, const float* __restrict__ h,
                     const float* __restrict__ W2l, const float* __restrict__ W2r,
                     const float* __restrict__ b2, float* __restrict__ embT) {
    int nT = min(hdr[0], T_CAP);
    int b  = blockIdx.x;
    if (b >= nT) return;
    int nE2 = min(hdr[2], E2_CAP);
    __shared__ int s_ui[256];
    __shared__ int s_cnt;
    __shared__ float mean[F];
    __shared__ float hr[F];
    int j = threadIdx.x;   // 128 threads
    if (j == 0) s_cnt = 0;
    __syncthreads();
    for (int i = j; i < nE2; i += 128) {    // parallel filter
        int2 ed = edges2[i];
        if (ed.y == b) {
            int ui = ((unsigned)ed.x < (unsigned)N) ? (u_map[ed.x] - 1) : -1;
            if ((unsigned)ui < (unsigned)U_CAP) {
                int p = atomicAdd(&s_cnt, 1);
                if (p < 256) s_ui[p] = ui;
            }
        }
    }
    __syncthreads();
    int cnt = min(s_cnt, 256);
    float sum = 0.0f;
    #pragma unroll 4
    for (int i = 0; i < cnt; ++i) sum += h[(size_t)s_ui[i] * F + j];
    float c = (s_cnt < 1) ? 1.0f : (float)s_cnt;   // true edge count
    mean[j] = sum / c;
    int node = t_node[b];
    int ui = ((unsigned)node < (unsigned)N) ? (u_map[node] - 1) : -1;
    hr[j] = ((unsigned)ui < (unsigned)U_CAP) ? h[(size_t)ui * F + j] : 0.0f;
    __syncthreads();
    float acc = b2[j];
    #pragma unroll 4
    for (int k = 0; k < F; ++k) {
        acc += mean[k] * W2l[k * F + j];
        acc += hr[k]   * W2r[k * F + j];
    }
    embT[(size_t)b * F + j] = acc;
}

static __device__ __forceinline__ float clamp999(int v) {
    return (float)(v < 0 ? 0 : (v > 999 ? 999 : v));
}

// ---- 6. fused MLP head: full 3F cat @ Wlin1, relu, @ Wlin2 (per k) ---------
__global__ void k_headf(const int* __restrict__ hdr, const int* __restrict__ ent2comp,
                        const float* __restrict__ embT,
                        const float* __restrict__ Wlin1, const float* __restrict__ blin1,
                        const float* __restrict__ Wlin2, const float* __restrict__ blin2,
                        float* __restrict__ out, int K) {
    __shared__ float s_cat[3 * F];
    __shared__ float s_part[4][F];
    __shared__ float red[F];
    int k = blockIdx.x;
    int tid = threadIdx.x;          // 512 threads
    int g = tid >> 7, j = tid & (F - 1);
    int c0 = ent2comp[0] & (T_CAP - 1);
    int c1 = ent2comp[1] & (T_CAP - 1);
    int ck = ent2comp[2 + k] & (T_CAP - 1);
    if (tid < F)          s_cat[tid] = embT[(size_t)c0 * F + tid];
    else if (tid < 2 * F) s_cat[tid] = embT[(size_t)c1 * F + (tid - F)];
    else if (tid < 3 * F) s_cat[tid] = embT[(size_t)ck * F + (tid - 2 * F)];
    __syncthreads();
    float acc = 0.0f;
    #pragma unroll 4
    for (int i = g * 96; i < (g + 1) * 96; ++i)   // 4 groups x 96 = 384 rows
        acc += s_cat[i] * Wlin1[i * F + j];
    s_part[g][j] = acc;
    __syncthreads();
    if (g == 0) {
        float hid = blin1[j] + s_part[0][j] + s_part[1][j] + s_part[2][j] + s_part[3][j];
        hid = (hid > 0.0f) ? hid : 0.0f;
        red[j] = hid * Wlin2[j];
    }
    __syncthreads();
    for (int s = 64; s > 0; s >>= 1) {
        if (tid < s) red[tid] += red[tid + s];
        __syncthreads();
    }
    if (tid == 0) {
        int nT = hdr[0], nU = hdr[1], nE2 = hdr[2];
        float D = 0.0f;  // inert when every stage count is sane
        if      (nT  < 1  || nT  > K + 2)  D = 1.0e6f + clamp999(nT) * 1e3f;
        else if (nU  < nT || nU  > U_CAP)  D = 2.0e6f + clamp999(nU / 10) * 1e3f;
        else if (nE2 < 1  || nE2 > E2_CAP) D = 3.0e6f + clamp999(nE2 / 10) * 1e3f;
        out[k] = red[0] + blin2[0] + D;
    }
}

extern "C" void kernel_launch(void* const* d_in, const int* in_sizes, int n_in,
                              void* d_out, int out_size, void* d_ws, size_t ws_size,
                              hipStream_t stream) {
    const float* x     = (const float*)d_in[0];
    const int*   eidx  = (const int*)d_in[1];
    const int*   curr  = (const int*)d_in[2];
    const int*   dest  = (const int*)d_in[3];
    const int*   nbr   = (const int*)d_in[4];
    const float* W1l   = (const float*)d_in[5];
    const float* W1r   = (const float*)d_in[6];
    const float* b1    = (const float*)d_in[7];
    const float* W2l   = (const float*)d_in[8];
    const float* W2r   = (const float*)d_in[9];
    const float* b2    = (const float*)d_in[10];
    const float* Wlin1 = (const float*)d_in[11];
    const float* blin1 = (const float*)d_in[12];
    const float* Wlin2 = (const float*)d_in[13];
    const float* blin2 = (const float*)d_in[14];
    float* out = (float*)d_out;

    const int N = in_sizes[0] / F;
    const int E = in_sizes[1] / 2;
    const int K = in_sizes[4];

    // ---- workspace layout ----
    char*  ws  = (char*)d_ws;
    size_t off = 0;
    int*      hdr      = (int*)(ws + off);      off += 64;
    int*      t_map    = (int*)(ws + off);      off += (size_t)4 * N;
    int*      u_map    = (int*)(ws + off);      off += (size_t)4 * N;
    int*      t_node   = (int*)(ws + off);      off += (size_t)4 * T_CAP;
    int*      ent2comp = (int*)(ws + off);      off += (size_t)4 * 256;
    int*      ulist    = (int*)(ws + off);      off += (size_t)4 * U_CAP;
    unsigned* t_bm     = (unsigned*)(ws + off); off += (size_t)4 * BM_WORDS;
    unsigned* u_bm     = (unsigned*)(ws + off); off += (size_t)4 * BM_WORDS;
    int*      deg1     = (int*)(ws + off);      off += (size_t)4 * U_CAP;
    size_t zero_bytes = off;                 // everything above starts at 0
    int*      bucket   = (int*)(ws + off);      off += (size_t)4 * U_CAP * BKT;   // 4 MB
    int2*     edges2   = (int2*)(ws + off);     off += (size_t)8 * E2_CAP;        // 1 MB
    float*    h        = (float*)(ws + off);    off += (size_t)4 * U_CAP * F;     // 4 MB
    float*    embT     = (float*)(ws + off);    off += (size_t)4 * T_CAP * F;

    int zero_words = (int)(zero_bytes / 4);
    k_zero<<<1024, 256, 0, stream>>>((int*)d_ws, zero_words);

    k_build<<<1, 128, 0, stream>>>(eidx, E, N, curr, dest, nbr, K, hdr, t_map, u_map,
                                   t_bm, u_bm, t_node, ent2comp, ulist);

    int sg = (E + EPBLK - 1) / EPBLK;   // 196 blocks: 64 edges/thread
    k_scan1<<<sg, SBLK, 0, stream>>>(eidx, E, N, t_map, u_map, t_bm, u_bm,
                                     hdr, edges2, ulist);
    k_scanU<<<sg, SBLK, 0, stream>>>(eidx, E, N, u_map, u_bm, hdr, deg1, bucket);
    k_l1<<<256, 128, 0, stream>>>(deg1, bucket, hdr, ulist, N, x, W1l, W1r, b1, h);
    k_l2<<<T_CAP, 128, 0, stream>>>(hdr, t_node, u_map, N, edges2, h, W2l, W2r, b2, embT);
    k_headf<<<K, 512, 0, stream>>>(hdr, ent2comp, embT, Wlin1, blin1, Wlin2, blin2, out, K);
}

// Round 17
// 256.387 us; speedup vs baseline: 1.4599x; 1.4599x over previous
//
#include <hip/hip_runtime.h>
#include <cstdint>

constexpr int F        = 128;     // feature width (F_in == H == 128)
constexpr int U_CAP    = 8192;    // cap on |T ∪ in-nbrs(T)|; expected ~2.2k
constexpr int T_CAP    = 128;     // cap on |targets|; actual <= 66
constexpr int E2_CAP   = 131072;  // cap on edges into T; expected ~2.1k
constexpr int BKT      = 128;     // bucket slots per U-node (in-degree ~Poisson(32))
constexpr int BM_WORDS = 3200;    // membership bitmap: supports N <= 102400
constexpr int SBLK     = 256;     // scan block size
constexpr int EPT      = 64;      // edges per thread (16x int4, interleaved)
constexpr int EPBLK    = SBLK * EPT;  // 16384 edges per block
constexpr int LCAP     = 512;     // LDS staging cap (4 KB)

// hdr: [0]=nT [1]=nU [2]=nE2 [3]=unused [4]=edge_is_int64 [5]=nbr_is_int64

__global__ void k_zero(int* p, int n) {
    int i = blockIdx.x * blockDim.x + threadIdx.x;
    int stride = gridDim.x * blockDim.x;
    for (; i < n; i += stride) p[i] = 0;
}

// ---- 1. parallel dedup of targets + int64 detection (one block) ------------
__global__ void k_build(const int* eidx, int E, int N,
                        const int* curr, const int* dest, const int* nbr, int K,
                        int* hdr, int* t_map, int* u_map,
                        unsigned* t_bm, unsigned* u_bm,
                        int* t_node, int* ent2comp, int* ulist) {
    __shared__ int s_e64, s_n64;
    int tid = threadIdx.x;
    if (tid == 0) { s_e64 = 1; s_n64 = 1; }
    __syncthreads();
    if (tid < 64 && eidx[2 * tid + 1] != 0) s_e64 = 0;
    if (tid < K / 2 && nbr[2 * tid + 1] != 0) s_n64 = 0;
    __syncthreads();
    int n64 = s_n64;
    if (tid == 0) { hdr[4] = s_e64; hdr[5] = s_n64; }

    int node = -1;
    if (tid < K + 2) {
        if (tid == 0)      node = curr[0];
        else if (tid == 1) node = dest[0];
        else               node = n64 ? nbr[2 * (tid - 2)] : nbr[tid - 2];
        if ((unsigned)node < (unsigned)N) {
            if (atomicCAS(&t_map[node], 0, -1) == 0) {   // claim: one winner
                int slot = atomicAdd(&hdr[0], 1);
                t_node[slot] = node;
                int uid = atomicAdd(&hdr[1], 1);
                ulist[uid] = node;
                atomicExch(&u_map[node], uid + 1);
                if (node < BM_WORDS * 32) {
                    atomicOr(&t_bm[node >> 5], 1u << (node & 31));
                    atomicOr(&u_bm[node >> 5], 1u << (node & 31));
                }
                atomicExch(&t_map[node], slot + 1);      // publish final slot
            }
        }
    }
    __syncthreads();
    if (tid < K + 2) {
        int v = ((unsigned)node < (unsigned)N) ? atomicAdd(&t_map[node], 0) : 1;
        ent2comp[tid] = v - 1;
    }
}

static __device__ __forceinline__ int esrc(const int* eidx, int E, int e, int is64) {
    return is64 ? eidx[2 * (size_t)e] : eidx[e];
}
static __device__ __forceinline__ int edst(const int* eidx, int E, int e, int is64) {
    return is64 ? eidx[2 * ((size_t)E + e)] : eidx[(size_t)E + e];
}

// ---- 2. scan: edges into T (64 edges/thread, branchless L1 probes) ---------
__global__ void k_scan1(const int* __restrict__ eidx, int E, int N,
                        const int* __restrict__ t_map, int* u_map,
                        const unsigned* __restrict__ t_bm, unsigned* u_bm,
                        int* hdr, int2* edges2, int* ulist) {
    __shared__ int l_cnt, l_base;
    __shared__ int2 l_buf[LCAP];
    int tid = threadIdx.x;
    if (tid == 0) l_cnt = 0;
    __syncthreads();
    int is64 = hdr[4];
    int be = blockIdx.x * EPBLK;
    int dv[EPT];
    #pragma unroll
    for (int r = 0; r < EPT / 4; ++r) {
        int e0 = be + (r * SBLK + tid) * 4;
        if (!is64 && e0 + 3 < E) {
            int4 d4 = *reinterpret_cast<const int4*>(eidx + (size_t)E + e0);
            dv[r*4+0] = d4.x; dv[r*4+1] = d4.y; dv[r*4+2] = d4.z; dv[r*4+3] = d4.w;
        } else {
            for (int q = 0; q < 4; ++q)
                dv[r*4+q] = (e0 + q < E) ? edst(eidx, E, e0 + q, is64) : -1;
        }
    }
    unsigned long long m = 0;
    #pragma unroll
    for (int i = 0; i < EPT; ++i) {
        int d  = dv[i];
        int dc = ((unsigned)d < (unsigned)N) ? d : 0;
        unsigned w = t_bm[dc >> 5];
        if ((unsigned)d < (unsigned)N && ((w >> (d & 31)) & 1))
            m |= (1ull << i);
    }
    while (m) {
        int i = __ffsll(m) - 1; m &= m - 1;
        int d = dv[i];
        int tm = t_map[d];
        if (tm <= 0) continue;
        int r = i >> 2, q = i & 3;
        int e = be + (r * SBLK + tid) * 4 + q;
        int s = esrc(eidx, E, e, is64);
        if ((unsigned)s >= (unsigned)N) continue;
        int p = atomicAdd(&l_cnt, 1);
        if (p < LCAP) l_buf[p] = make_int2(s, tm - 1);
        else {
            int gp = atomicAdd(&hdr[2], 1);
            if (gp < E2_CAP) edges2[gp] = make_int2(s, tm - 1);
        }
        if (atomicCAS(&u_map[s], 0, -1) == 0) {
            int id = atomicAdd(&hdr[1], 1);
            if (id < U_CAP) ulist[id] = s;
            if (s < BM_WORDS * 32) atomicOr(&u_bm[s >> 5], 1u << (s & 31));
            __threadfence();
            atomicExch(&u_map[s], id + 1);
        }
    }
    __syncthreads();
    int c = min(l_cnt, LCAP);
    if (c > 0) {
        if (tid == 0) l_base = atomicAdd(&hdr[2], c);
        __syncthreads();
        for (int i = tid; i < c; i += SBLK) {
            int gp = l_base + i;
            if (gp < E2_CAP) edges2[gp] = l_buf[i];
        }
    }
}

// ---- 3. scan: edges into U -> per-dest buckets (64 edges/thread) -----------
__global__ void k_scanU(const int* __restrict__ eidx, int E, int N,
                        const int* __restrict__ u_map,
                        const unsigned* __restrict__ u_bm,
                        const int* __restrict__ hdr,
                        int* deg1, int* bucket) {
    int tid = threadIdx.x;
    int is64 = hdr[4];
    int be = blockIdx.x * EPBLK;
    int dv[EPT];
    #pragma unroll
    for (int r = 0; r < EPT / 4; ++r) {
        int e0 = be + (r * SBLK + tid) * 4;
        if (!is64 && e0 + 3 < E) {
            int4 d4 = *reinterpret_cast<const int4*>(eidx + (size_t)E + e0);
            dv[r*4+0] = d4.x; dv[r*4+1] = d4.y; dv[r*4+2] = d4.z; dv[r*4+3] = d4.w;
        } else {
            for (int q = 0; q < 4; ++q)
                dv[r*4+q] = (e0 + q < E) ? edst(eidx, E, e0 + q, is64) : -1;
        }
    }
    unsigned long long m = 0;
    #pragma unroll
    for (int i = 0; i < EPT; ++i) {
        int d  = dv[i];
        int dc = ((unsigned)d < (unsigned)N) ? d : 0;
        unsigned w = u_bm[dc >> 5];
        if ((unsigned)d < (unsigned)N && ((w >> (d & 31)) & 1))
            m |= (1ull << i);
    }
    while (m) {
        int i = __ffsll(m) - 1; m &= m - 1;
        int d = dv[i];
        int um = u_map[d];
        if (um <= 0 || um > U_CAP) continue;
        int r = i >> 2, q = i & 3;
        int e = be + (r * SBLK + tid) * 4 + q;
        int s = esrc(eidx, E, e, is64);
        if ((unsigned)s >= (unsigned)N) continue;
        int slot = um - 1;
        int pos = atomicAdd(&deg1[slot], 1);   // scalar atomic, 2.2k addresses
        if (pos < BKT) bucket[(size_t)slot * BKT + pos] = s;
    }
}

// ---- 4. fused layer-1: bucket mean + GEMV -> h (per U-node) ----------------
__global__ void k_l1(const int* __restrict__ deg1, const int* __restrict__ bucket,
                     const int* __restrict__ hdr, const int* __restrict__ ulist, int N,
                     const float* __restrict__ x,
                     const float* __restrict__ W1l, const float* __restrict__ W1r,
                     const float* __restrict__ b1, float* __restrict__ h) {
    int nU = min(hdr[1], U_CAP);
    __shared__ int s_src[BKT];
    __shared__ float mean[F];
    __shared__ float xr[F];
    int j = threadIdx.x;   // 128 threads
    for (int b = blockIdx.x; b < nU; b += gridDim.x) {
        int dg = deg1[b];
        int stored = min(dg, BKT);
        if (j < stored) s_src[j] = bucket[(size_t)b * BKT + j];
        int node = ulist[b];
        xr[j] = ((unsigned)node < (unsigned)N) ? x[(size_t)node * F + j] : 0.0f;
        __syncthreads();
        float acc = 0.0f;
        #pragma unroll 4
        for (int i = 0; i < stored; ++i) {
            int s = s_src[i];
            if ((unsigned)s < (unsigned)N) acc += x[(size_t)s * F + j];
        }
        float c = (dg < 1) ? 1.0f : (float)dg;
        mean[j] = acc / c;
        __syncthreads();
        float o = b1[j];
        #pragma unroll 4
        for (int k = 0; k < F; ++k) {
            o += mean[k] * W1l[k * F + j];
            o += xr[k]   * W1r[k * F + j];
        }
        h[(size_t)b * F + j] = (o > 0.0f) ? o : 0.0f;
        __syncthreads();   // protect LDS before next node
    }
}

// ---- 5. fused layer-2: filter edges2 + mean + GEMV -> embT (per target) ----
__global__ void k_l2(const int* __restrict__ hdr, const int* __restrict__ t_node,
                     const int* __restrict__ u_map, int N,
                     const int2* __restrict__ edges2, const float* __restrict__ h,
                     const float* __restrict__ W2l, const float* __restrict__ W2r,
                     const float* __restrict__ b2, float* __restrict__ embT) {
    int nT = min(hdr[0], T_CAP);
    int b  = blockIdx.x;
    if (b >= nT) return;
    int nE2 = min(hdr[2], E2_CAP);
    __shared__ int s_ui[256];
    __shared__ int s_cnt;
    __shared__ float mean[F];
    __shared__ float hr[F];
    int j = threadIdx.x;   // 128 threads
    if (j == 0) s_cnt = 0;
    __syncthreads();
    for (int i = j; i < nE2; i += 128) {    // parallel filter
        int2 ed = edges2[i];
        if (ed.y == b) {
            int ui = ((unsigned)ed.x < (unsigned)N) ? (u_map[ed.x] - 1) : -1;
            if ((unsigned)ui < (unsigned)U_CAP) {
                int p = atomicAdd(&s_cnt, 1);
                if (p < 256) s_ui[p] = ui;
            }
        }
    }
    __syncthreads();
    int cnt = min(s_cnt, 256);
    float sum = 0.0f;
    #pragma unroll 4
    for (int i = 0; i < cnt; ++i) sum += h[(size_t)s_ui[i] * F + j];
    float c = (s_cnt < 1) ? 1.0f : (float)s_cnt;   // true edge count
    mean[j] = sum / c;
    int node = t_node[b];
    int ui = ((unsigned)node < (unsigned)N) ? (u_map[node] - 1) : -1;
    hr[j] = ((unsigned)ui < (unsigned)U_CAP) ? h[(size_t)ui * F + j] : 0.0f;
    __syncthreads();
    float acc = b2[j];
    #pragma unroll 4
    for (int k = 0; k < F; ++k) {
        acc += mean[k] * W2l[k * F + j];
        acc += hr[k]   * W2r[k * F + j];
    }
    embT[(size_t)b * F + j] = acc;
}

static __device__ __forceinline__ float clamp999(int v) {
    return (float)(v < 0 ? 0 : (v > 999 ? 999 : v));
}

// ---- 6. fused MLP head: full 3F cat @ Wlin1, relu, @ Wlin2 (per k) ---------
__global__ void k_headf(const int* __restrict__ hdr, const int* __restrict__ ent2comp,
                        const float* __restrict__ embT,
                        const float* __restrict__ Wlin1, const float* __restrict__ blin1,
                        const float* __restrict__ Wlin2, const float* __restrict__ blin2,
                        float* __restrict__ out, int K) {
    __shared__ float s_cat[3 * F];
    __shared__ float s_part[4][F];
    __shared__ float red[F];
    int k = blockIdx.x;
    int tid = threadIdx.x;          // 512 threads
    int g = tid >> 7, j = tid & (F - 1);
    int c0 = ent2comp[0] & (T_CAP - 1);
    int c1 = ent2comp[1] & (T_CAP - 1);
    int ck = ent2comp[2 + k] & (T_CAP - 1);
    if (tid < F)          s_cat[tid] = embT[(size_t)c0 * F + tid];
    else if (tid < 2 * F) s_cat[tid] = embT[(size_t)c1 * F + (tid - F)];
    else if (tid < 3 * F) s_cat[tid] = embT[(size_t)ck * F + (tid - 2 * F)];
    __syncthreads();
    float acc = 0.0f;
    #pragma unroll 4
    for (int i = g * 96; i < (g + 1) * 96; ++i)   // 4 groups x 96 = 384 rows
        acc += s_cat[i] * Wlin1[i * F + j];
    s_part[g][j] = acc;
    __syncthreads();
    if (g == 0) {
        float hid = blin1[j] + s_part[0][j] + s_part[1][j] + s_part[2][j] + s_part[3][j];
        hid = (hid > 0.0f) ? hid : 0.0f;
        red[j] = hid * Wlin2[j];
    }
    __syncthreads();
    for (int s = 64; s > 0; s >>= 1) {
        if (tid < s) red[tid] += red[tid + s];
        __syncthreads();
    }
    if (tid == 0) {
        int nT = hdr[0], nU = hdr[1], nE2 = hdr[2];
        float D = 0.0f;  // inert when every stage count is sane
        if      (nT  < 1  || nT  > K + 2)  D = 1.0e6f + clamp999(nT) * 1e3f;
        else if (nU  < nT || nU  > U_CAP)  D = 2.0e6f + clamp999(nU / 10) * 1e3f;
        else if (nE2 < 1  || nE2 > E2_CAP) D = 3.0e6f + clamp999(nE2 / 10) * 1e3f;
        out[k] = red[0] + blin2[0] + D;
    }
}

extern "C" void kernel_launch(void* const* d_in, const int* in_sizes, int n_in,
                              void* d_out, int out_size, void* d_ws, size_t ws_size,
                              hipStream_t stream) {
    const float* x     = (const float*)d_in[0];
    const int*   eidx  = (const int*)d_in[1];
    const int*   curr  = (const int*)d_in[2];
    const int*   dest  = (const int*)d_in[3];
    const int*   nbr   = (const int*)d_in[4];
    const float* W1l   = (const float*)d_in[5];
    const float* W1r   = (const float*)d_in[6];
    const float* b1    = (const float*)d_in[7];
    const float* W2l   = (const float*)d_in[8];
    const float* W2r   = (const float*)d_in[9];
    const float* b2    = (const float*)d_in[10];
    const float* Wlin1 = (const float*)d_in[11];
    const float* blin1 = (const float*)d_in[12];
    const float* Wlin2 = (const float*)d_in[13];
    const float* blin2 = (const float*)d_in[14];
    float* out = (float*)d_out;

    const int N = in_sizes[0] / F;
    const int E = in_sizes[1] / 2;
    const int K = in_sizes[4];

    // ---- workspace layout ----
    char*  ws  = (char*)d_ws;
    size_t off = 0;
    int*      hdr      = (int*)(ws + off);      off += 64;
    int*      t_map    = (int*)(ws + off);      off += (size_t)4 * N;
    int*      u_map    = (int*)(ws + off);      off += (size_t)4 * N;
    int*      t_node   = (int*)(ws + off);      off += (size_t)4 * T_CAP;
    int*      ent2comp = (int*)(ws + off);      off += (size_t)4 * 256;
    int*      ulist    = (int*)(ws + off);      off += (size_t)4 * U_CAP;
    unsigned* t_bm     = (unsigned*)(ws + off); off += (size_t)4 * BM_WORDS;
    unsigned* u_bm     = (unsigned*)(ws + off); off += (size_t)4 * BM_WORDS;
    int*      deg1     = (int*)(ws + off);      off += (size_t)4 * U_CAP;
    size_t zero_bytes = off;                 // everything above starts at 0
    int*      bucket   = (int*)(ws + off);      off += (size_t)4 * U_CAP * BKT;   // 4 MB
    int2*     edges2   = (int2*)(ws + off);     off += (size_t)8 * E2_CAP;        // 1 MB
    float*    h        = (float*)(ws + off);    off += (size_t)4 * U_CAP * F;     // 4 MB
    float*    embT     = (float*)(ws + off);    off += (size_t)4 * T_CAP * F;

    int zero_words = (int)(zero_bytes / 4);
    k_zero<<<1024, 256, 0, stream>>>((int*)d_ws, zero_words);

    k_build<<<1, 128, 0, stream>>>(eidx, E, N, curr, dest, nbr, K, hdr, t_map, u_map,
                                   t_bm, u_bm, t_node, ent2comp, ulist);

    int sg = (E + EPBLK - 1) / EPBLK;   // 196 blocks: 64 edges/thread
    k_scan1<<<sg, SBLK, 0, stream>>>(eidx, E, N, t_map, u_map, t_bm, u_bm,
                                     hdr, edges2, ulist);
    k_scanU<<<sg, SBLK, 0, stream>>>(eidx, E, N, u_map, u_bm, hdr, deg1, bucket);
    k_l1<<<2048, 128, 0, stream>>>(deg1, bucket, hdr, ulist, N, x, W1l, W1r, b1, h);
    k_l2<<<T_CAP, 128, 0, stream>>>(hdr, t_node, u_map, N, edges2, h, W2l, W2r, b2, embT);
    k_headf<<<K, 512, 0, stream>>>(hdr, ent2comp, embT, Wlin1, blin1, Wlin2, blin2, out, K);
}

// Round 18
// 244.351 us; speedup vs baseline: 1.5318x; 1.0493x over previous
//
#include <hip/hip_runtime.h>
#include <cstdint>

constexpr int F        = 128;     // feature width (F_in == H == 128)
constexpr int U_CAP    = 8192;    // cap on |T ∪ in-nbrs(T)|; expected ~2.2k
constexpr int T_CAP    = 128;     // cap on |targets|; actual <= 66
constexpr int E2_CAP   = 131072;  // cap on edges into T; expected ~2.1k
constexpr int BKT      = 128;     // bucket slots per U-node (in-degree ~Poisson(32))
constexpr int BM_WORDS = 3200;    // membership bitmap: supports N <= 102400
constexpr int SBLK     = 256;     // scan block size
constexpr int EPT      = 64;      // edges per thread (16x int4, interleaved)
constexpr int EPBLK    = SBLK * EPT;  // 16384 edges per block
constexpr int LCAP     = 512;     // LDS staging cap (4 KB)

// hdr: [0]=nT [1]=nU [2]=nE2 [3]=unused [4]=edge_is_int64 [5]=nbr_is_int64

__global__ void k_zero(int* p, int n) {
    int i = blockIdx.x * blockDim.x + threadIdx.x;
    int stride = gridDim.x * blockDim.x;
    for (; i < n; i += stride) p[i] = 0;
}

// ---- 1. parallel dedup of targets + int64 detection (one block) ------------
__global__ void k_build(const int* eidx, int E, int N,
                        const int* curr, const int* dest, const int* nbr, int K,
                        int* hdr, int* t_map, int* u_map,
                        unsigned* t_bm, unsigned* u_bm,
                        int* t_node, int* ent2comp, int* ulist) {
    __shared__ int s_e64, s_n64;
    int tid = threadIdx.x;
    if (tid == 0) { s_e64 = 1; s_n64 = 1; }
    __syncthreads();
    if (tid < 64 && eidx[2 * tid + 1] != 0) s_e64 = 0;
    if (tid < K / 2 && nbr[2 * tid + 1] != 0) s_n64 = 0;
    __syncthreads();
    int n64 = s_n64;
    if (tid == 0) { hdr[4] = s_e64; hdr[5] = s_n64; }

    int node = -1;
    if (tid < K + 2) {
        if (tid == 0)      node = curr[0];
        else if (tid == 1) node = dest[0];
        else               node = n64 ? nbr[2 * (tid - 2)] : nbr[tid - 2];
        if ((unsigned)node < (unsigned)N) {
            if (atomicCAS(&t_map[node], 0, -1) == 0) {   // claim: one winner
                int slot = atomicAdd(&hdr[0], 1);
                t_node[slot] = node;
                int uid = atomicAdd(&hdr[1], 1);
                ulist[uid] = node;
                atomicExch(&u_map[node], uid + 1);
                if (node < BM_WORDS * 32) {
                    atomicOr(&t_bm[node >> 5], 1u << (node & 31));
                    atomicOr(&u_bm[node >> 5], 1u << (node & 31));
                }
                atomicExch(&t_map[node], slot + 1);      // publish final slot
            }
        }
    }
    __syncthreads();
    if (tid < K + 2) {
        int v = ((unsigned)node < (unsigned)N) ? atomicAdd(&t_map[node], 0) : 1;
        ent2comp[tid] = v - 1;
    }
}

static __device__ __forceinline__ int esrc(const int* eidx, int E, int e, int is64) {
    return is64 ? eidx[2 * (size_t)e] : eidx[e];
}
static __device__ __forceinline__ int edst(const int* eidx, int E, int e, int is64) {
    return is64 ? eidx[2 * ((size_t)E + e)] : eidx[(size_t)E + e];
}

// ---- 2. scan: edges into T (64 edges/thread, branchless L1 probes) ---------
__global__ void k_scan1(const int* __restrict__ eidx, int E, int N,
                        const int* __restrict__ t_map, int* u_map,
                        const unsigned* __restrict__ t_bm, unsigned* u_bm,
                        int* hdr, int2* edges2, int* ulist) {
    __shared__ int l_cnt, l_base;
    __shared__ int2 l_buf[LCAP];
    int tid = threadIdx.x;
    if (tid == 0) l_cnt = 0;
    __syncthreads();
    int is64 = hdr[4];
    int be = blockIdx.x * EPBLK;
    int dv[EPT];
    #pragma unroll
    for (int r = 0; r < EPT / 4; ++r) {
        int e0 = be + (r * SBLK + tid) * 4;
        if (!is64 && e0 + 3 < E) {
            int4 d4 = *reinterpret_cast<const int4*>(eidx + (size_t)E + e0);
            dv[r*4+0] = d4.x; dv[r*4+1] = d4.y; dv[r*4+2] = d4.z; dv[r*4+3] = d4.w;
        } else {
            for (int q = 0; q < 4; ++q)
                dv[r*4+q] = (e0 + q < E) ? edst(eidx, E, e0 + q, is64) : -1;
        }
    }
    unsigned long long m = 0;
    #pragma unroll
    for (int i = 0; i < EPT; ++i) {
        int d  = dv[i];
        int dc = ((unsigned)d < (unsigned)N) ? d : 0;
        unsigned w = t_bm[dc >> 5];
        if ((unsigned)d < (unsigned)N && ((w >> (d & 31)) & 1))
            m |= (1ull << i);
    }
    while (m) {
        int i = __ffsll(m) - 1; m &= m - 1;
        int d = dv[i];
        int tm = t_map[d];
        if (tm <= 0) continue;
        int r = i >> 2, q = i & 3;
        int e = be + (r * SBLK + tid) * 4 + q;
        int s = esrc(eidx, E, e, is64);
        if ((unsigned)s >= (unsigned)N) continue;
        int p = atomicAdd(&l_cnt, 1);
        if (p < LCAP) l_buf[p] = make_int2(s, tm - 1);
        else {
            int gp = atomicAdd(&hdr[2], 1);
            if (gp < E2_CAP) edges2[gp] = make_int2(s, tm - 1);
        }
        if (atomicCAS(&u_map[s], 0, -1) == 0) {
            int id = atomicAdd(&hdr[1], 1);
            if (id < U_CAP) ulist[id] = s;
            if (s < BM_WORDS * 32) atomicOr(&u_bm[s >> 5], 1u << (s & 31));
            __threadfence();
            atomicExch(&u_map[s], id + 1);
        }
    }
    __syncthreads();
    int c = min(l_cnt, LCAP);
    if (c > 0) {
        if (tid == 0) l_base = atomicAdd(&hdr[2], c);
        __syncthreads();
        for (int i = tid; i < c; i += SBLK) {
            int gp = l_base + i;
            if (gp < E2_CAP) edges2[gp] = l_buf[i];
        }
    }
}

// ---- 3. scan: edges into U -> per-dest buckets (64 edges/thread) -----------
__global__ void k_scanU(const int* __restrict__ eidx, int E, int N,
                        const int* __restrict__ u_map,
                        const unsigned* __restrict__ u_bm,
                        const int* __restrict__ hdr,
                        int* deg1, int* bucket) {
    int tid = threadIdx.x;
    int is64 = hdr[4];
    int be = blockIdx.x * EPBLK;
    int dv[EPT];
    #pragma unroll
    for (int r = 0; r < EPT / 4; ++r) {
        int e0 = be + (r * SBLK + tid) * 4;
        if (!is64 && e0 + 3 < E) {
            int4 d4 = *reinterpret_cast<const int4*>(eidx + (size_t)E + e0);
            dv[r*4+0] = d4.x; dv[r*4+1] = d4.y; dv[r*4+2] = d4.z; dv[r*4+3] = d4.w;
        } else {
            for (int q = 0; q < 4; ++q)
                dv[r*4+q] = (e0 + q < E) ? edst(eidx, E, e0 + q, is64) : -1;
        }
    }
    unsigned long long m = 0;
    #pragma unroll
    for (int i = 0; i < EPT; ++i) {
        int d  = dv[i];
        int dc = ((unsigned)d < (unsigned)N) ? d : 0;
        unsigned w = u_bm[dc >> 5];
        if ((unsigned)d < (unsigned)N && ((w >> (d & 31)) & 1))
            m |= (1ull << i);
    }
    while (m) {
        int i = __ffsll(m) - 1; m &= m - 1;
        int d = dv[i];
        int um = u_map[d];
        if (um <= 0 || um > U_CAP) continue;
        int r = i >> 2, q = i & 3;
        int e = be + (r * SBLK + tid) * 4 + q;
        int s = esrc(eidx, E, e, is64);
        if ((unsigned)s >= (unsigned)N) continue;
        int slot = um - 1;
        int pos = atomicAdd(&deg1[slot], 1);   // scalar atomic, 2.2k addresses
        if (pos < BKT) bucket[(size_t)slot * BKT + pos] = s;
    }
}

// ---- 4. fused layer-1: float4 bucket gather + GEMV -> h (per U-node) -------
__global__ void k_l1(const int* __restrict__ deg1, const int* __restrict__ bucket,
                     const int* __restrict__ hdr, const int* __restrict__ ulist, int N,
                     const float* __restrict__ x,
                     const float* __restrict__ W1l, const float* __restrict__ W1r,
                     const float* __restrict__ b1, float* __restrict__ h) {
    int nU = min(hdr[1], U_CAP);
    __shared__ int s_src[BKT];
    __shared__ float4 s_part[4][32];
    __shared__ float mean[F];
    __shared__ float xr[F];
    int j = threadIdx.x;   // 128 threads
    int g = j >> 5, l = j & 31;   // 4 row-groups x 32 lanes
    for (int b = blockIdx.x; b < nU; b += gridDim.x) {
        int dg = deg1[b];
        int stored = min(dg, BKT);
        if (j < stored) s_src[j] = bucket[(size_t)b * BKT + j];
        int node = ulist[b];
        xr[j] = ((unsigned)node < (unsigned)N) ? x[(size_t)node * F + j] : 0.0f;
        __syncthreads();
        // gather: group g accumulates rows i = g, g+4, g+8, ... ; lane l
        // loads float4 #l of the row -> one full 512 B row per quarter-wave op
        float4 a4 = make_float4(0.f, 0.f, 0.f, 0.f);
        #pragma unroll 4
        for (int i = g; i < stored; i += 4) {
            int s = s_src[i];
            if ((unsigned)s < (unsigned)N) {
                float4 v = reinterpret_cast<const float4*>(x + (size_t)s * F)[l];
                a4.x += v.x; a4.y += v.y; a4.z += v.z; a4.w += v.w;
            }
        }
        s_part[g][l] = a4;
        __syncthreads();
        // combine 4 group-partials; column j -> lane j>>2, component j&3
        float c = (dg < 1) ? 1.0f : (float)dg;
        int lp = j >> 2, cc = j & 3;
        float sum = 0.0f;
        #pragma unroll
        for (int gg = 0; gg < 4; ++gg) {
            float4 p = s_part[gg][lp];
            sum += (cc == 0) ? p.x : (cc == 1) ? p.y : (cc == 2) ? p.z : p.w;
        }
        mean[j] = sum / c;
        __syncthreads();
        float o = b1[j];
        #pragma unroll 4
        for (int k = 0; k < F; ++k) {
            o += mean[k] * W1l[k * F + j];
            o += xr[k]   * W1r[k * F + j];
        }
        h[(size_t)b * F + j] = (o > 0.0f) ? o : 0.0f;
        __syncthreads();   // protect LDS before next node
    }
}

// ---- 5. fused layer-2: filter edges2 + mean + GEMV -> embT (per target) ----
__global__ void k_l2(const int* __restrict__ hdr, const int* __restrict__ t_node,
                     const int* __restrict__ u_map, int N,
                     const int2* __restrict__ edges2, const float* __restrict__ h,
                     const float* __restrict__ W2l, const float* __restrict__ W2r,
                     const float* __restrict__ b2, float* __restrict__ embT) {
    int nT = min(hdr[0], T_CAP);
    int b  = blockIdx.x;
    if (b >= nT) return;
    int nE2 = min(hdr[2], E2_CAP);
    __shared__ int s_ui[256];
    __shared__ int s_cnt;
    __shared__ float mean[F];
    __shared__ float hr[F];
    int j = threadIdx.x;   // 128 threads
    if (j == 0) s_cnt = 0;
    __syncthreads();
    for (int i = j; i < nE2; i += 128) {    // parallel filter
        int2 ed = edges2[i];
        if (ed.y == b) {
            int ui = ((unsigned)ed.x < (unsigned)N) ? (u_map[ed.x] - 1) : -1;
            if ((unsigned)ui < (unsigned)U_CAP) {
                int p = atomicAdd(&s_cnt, 1);
                if (p < 256) s_ui[p] = ui;
            }
        }
    }
    __syncthreads();
    int cnt = min(s_cnt, 256);
    float sum = 0.0f;
    #pragma unroll 4
    for (int i = 0; i < cnt; ++i) sum += h[(size_t)s_ui[i] * F + j];
    float c = (s_cnt < 1) ? 1.0f : (float)s_cnt;   // true edge count
    mean[j] = sum / c;
    int node = t_node[b];
    int ui = ((unsigned)node < (unsigned)N) ? (u_map[node] - 1) : -1;
    hr[j] = ((unsigned)ui < (unsigned)U_CAP) ? h[(size_t)ui * F + j] : 0.0f;
    __syncthreads();
    float acc = b2[j];
    #pragma unroll 4
    for (int k = 0; k < F; ++k) {
        acc += mean[k] * W2l[k * F + j];
        acc += hr[k]   * W2r[k * F + j];
    }
    embT[(size_t)b * F + j] = acc;
}

static __device__ __forceinline__ float clamp999(int v) {
    return (float)(v < 0 ? 0 : (v > 999 ? 999 : v));
}

// ---- 6. fused MLP head: full 3F cat @ Wlin1, relu, @ Wlin2 (per k) ---------
__global__ void k_headf(const int* __restrict__ hdr, const int* __restrict__ ent2comp,
                        const float* __restrict__ embT,
                        const float* __restrict__ Wlin1, const float* __restrict__ blin1,
                        const float* __restrict__ Wlin2, const float* __restrict__ blin2,
                        float* __restrict__ out, int K) {
    __shared__ float s_cat[3 * F];
    __shared__ float s_part[4][F];
    __shared__ float red[F];
    int k = blockIdx.x;
    int tid = threadIdx.x;          // 512 threads
    int g = tid >> 7, j = tid & (F - 1);
    int c0 = ent2comp[0] & (T_CAP - 1);
    int c1 = ent2comp[1] & (T_CAP - 1);
    int ck = ent2comp[2 + k] & (T_CAP - 1);
    if (tid < F)          s_cat[tid] = embT[(size_t)c0 * F + tid];
    else if (tid < 2 * F) s_cat[tid] = embT[(size_t)c1 * F + (tid - F)];
    else if (tid < 3 * F) s_cat[tid] = embT[(size_t)ck * F + (tid - 2 * F)];
    __syncthreads();
    float acc = 0.0f;
    #pragma unroll 4
    for (int i = g * 96; i < (g + 1) * 96; ++i)   // 4 groups x 96 = 384 rows
        acc += s_cat[i] * Wlin1[i * F + j];
    s_part[g][j] = acc;
    __syncthreads();
    if (g == 0) {
        float hid = blin1[j] + s_part[0][j] + s_part[1][j] + s_part[2][j] + s_part[3][j];
        hid = (hid > 0.0f) ? hid : 0.0f;
        red[j] = hid * Wlin2[j];
    }
    __syncthreads();
    for (int s = 64; s > 0; s >>= 1) {
        if (tid < s) red[tid] += red[tid + s];
        __syncthreads();
    }
    if (tid == 0) {
        int nT = hdr[0], nU = hdr[1], nE2 = hdr[2];
        float D = 0.0f;  // inert when every stage count is sane
        if      (nT  < 1  || nT  > K + 2)  D = 1.0e6f + clamp999(nT) * 1e3f;
        else if (nU  < nT || nU  > U_CAP)  D = 2.0e6f + clamp999(nU / 10) * 1e3f;
        else if (nE2 < 1  || nE2 > E2_CAP) D = 3.0e6f + clamp999(nE2 / 10) * 1e3f;
        out[k] = red[0] + blin2[0] + D;
    }
}

extern "C" void kernel_launch(void* const* d_in, const int* in_sizes, int n_in,
                              void* d_out, int out_size, void* d_ws, size_t ws_size,
                              hipStream_t stream) {
    const float* x     = (const float*)d_in[0];
    const int*   eidx  = (const int*)d_in[1];
    const int*   curr  = (const int*)d_in[2];
    const int*   dest  = (const int*)d_in[3];
    const int*   nbr   = (const int*)d_in[4];
    const float* W1l   = (const float*)d_in[5];
    const float* W1r   = (const float*)d_in[6];
    const float* b1    = (const float*)d_in[7];
    const float* W2l   = (const float*)d_in[8];
    const float* W2r   = (const float*)d_in[9];
    const float* b2    = (const float*)d_in[10];
    const float* Wlin1 = (const float*)d_in[11];
    const float* blin1 = (const float*)d_in[12];
    const float* Wlin2 = (const float*)d_in[13];
    const float* blin2 = (const float*)d_in[14];
    float* out = (float*)d_out;

    const int N = in_sizes[0] / F;
    const int E = in_sizes[1] / 2;
    const int K = in_sizes[4];

    // ---- workspace layout ----
    char*  ws  = (char*)d_ws;
    size_t off = 0;
    int*      hdr      = (int*)(ws + off);      off += 64;
    int*      t_map    = (int*)(ws + off);      off += (size_t)4 * N;
    int*      u_map    = (int*)(ws + off);      off += (size_t)4 * N;
    int*      t_node   = (int*)(ws + off);      off += (size_t)4 * T_CAP;
    int*      ent2comp = (int*)(ws + off);      off += (size_t)4 * 256;
    int*      ulist    = (int*)(ws + off);      off += (size_t)4 * U_CAP;
    unsigned* t_bm     = (unsigned*)(ws + off); off += (size_t)4 * BM_WORDS;
    unsigned* u_bm     = (unsigned*)(ws + off); off += (size_t)4 * BM_WORDS;
    int*      deg1     = (int*)(ws + off);      off += (size_t)4 * U_CAP;
    size_t zero_bytes = off;                 // everything above starts at 0
    int*      bucket   = (int*)(ws + off);      off += (size_t)4 * U_CAP * BKT;   // 4 MB
    int2*     edges2   = (int2*)(ws + off);     off += (size_t)8 * E2_CAP;        // 1 MB
    float*    h        = (float*)(ws + off);    off += (size_t)4 * U_CAP * F;     // 4 MB
    float*    embT     = (float*)(ws + off);    off += (size_t)4 * T_CAP * F;

    int zero_words = (int)(zero_bytes / 4);
    k_zero<<<1024, 256, 0, stream>>>((int*)d_ws, zero_words);

    k_build<<<1, 128, 0, stream>>>(eidx, E, N, curr, dest, nbr, K, hdr, t_map, u_map,
                                   t_bm, u_bm, t_node, ent2comp, ulist);

    int sg = (E + EPBLK - 1) / EPBLK;   // 196 blocks: 64 edges/thread
    k_scan1<<<sg, SBLK, 0, stream>>>(eidx, E, N, t_map, u_map, t_bm, u_bm,
                                     hdr, edges2, ulist);
    k_scanU<<<sg, SBLK, 0, stream>>>(eidx, E, N, u_map, u_bm, hdr, deg1, bucket);
    k_l1<<<2048, 128, 0, stream>>>(deg1, bucket, hdr, ulist, N, x, W1l, W1r, b1, h);
    k_l2<<<T_CAP, 128, 0, stream>>>(hdr, t_node, u_map, N, edges2, h, W2l, W2r, b2, embT);
    k_headf<<<K, 512, 0, stream>>>(hdr, ent2comp, embT, Wlin1, blin1, Wlin2, blin2, out, K);
}